// Round 1
// baseline (509.923 us; speedup 1.0000x reference)
//
#include <hip/hip_runtime.h>

namespace {
constexpr int D_  = 4;
constexpr int ND  = 9;    // 2D+1
constexpr int NK  = 81;
constexpr int B_  = 4, C_ = 64, H_ = 192, W_ = 448;
constexpr int TH  = 16;   // tile rows (y)
constexpr int TXN = 16;   // threads along x
constexpr int PX  = 2;    // pixels per thread along x
constexpr int TW  = TXN * PX;        // 32
constexpr int CCH = 8;               // channels staged per round
constexpr int HR  = TH + 2 * D_;     // 24 halo rows
constexpr int HC  = TW + 2 * D_;     // 40 halo cols
constexpr int HCP = 42;              // padded LDS row stride (even -> b64 aligned)
constexpr int NTHREADS = TH * TXN;   // 256
}

__global__ __launch_bounds__(NTHREADS, 2)
void corr81_kernel(const float* __restrict__ f1, const float* __restrict__ f2,
                   float* __restrict__ out)
{
    __shared__ float s2[CCH * HR * HCP];

    const int tid = threadIdx.x;
    const int tx  = tid & (TXN - 1);
    const int ty  = tid >> 4;

    const int x0 = blockIdx.x * TW;
    const int y0 = blockIdx.y * TH;
    const int b  = blockIdx.z;

    const int gx = x0 + tx * PX;
    const int gy = y0 + ty;

    float acc[ND][ND][PX];
#pragma unroll
    for (int i = 0; i < ND; ++i)
#pragma unroll
        for (int j = 0; j < ND; ++j)
#pragma unroll
            for (int p = 0; p < PX; ++p) acc[i][j][p] = 0.f;

    const size_t plane = (size_t)H_ * W_;
    const float* f1p = f1 + (((size_t)b * C_) * H_ + gy) * W_ + gx;

    // this thread's LDS compute base (channel 0, dy 0)
    const float* sbase = s2 + ty * HCP + tx * PX;

    for (int cc = 0; cc < C_; cc += CCH) {
        __syncthreads();  // protect previous round's LDS reads

        // ---- stage CCH channels of feat2 halo tile (float2 granularity) ----
        // total float2 elements: CCH * HR * (HC/2) = 8*24*20 = 3840 = 256*15
#pragma unroll
        for (int i = 0; i < 15; ++i) {
            int l   = tid + NTHREADS * i;
            int c   = l / (HR * (HC / 2));            // /480
            int rem = l - c * (HR * (HC / 2));
            int r   = rem / (HC / 2);                 // /20
            int p   = rem - r * (HC / 2);
            int col = p * 2;
            int yy  = y0 - D_ + r;
            int xx  = x0 - D_ + col;                  // always even -> no straddle
            float2 v = make_float2(0.f, 0.f);
            if (yy >= 0 && yy < H_ && xx >= 0 && xx < W_) {
                v = *(const float2*)(f2 + (((size_t)b * C_ + cc + c) * H_ + yy) * W_ + xx);
            }
            *(float2*)&s2[(c * HR + r) * HCP + col] = v;
        }
        __syncthreads();

        // ---- preload feat1 values for these channels (coalesced, read-once) ----
        float2 a[CCH];
#pragma unroll
        for (int c = 0; c < CCH; ++c)
            a[c] = *(const float2*)(f1p + (size_t)(cc + c) * plane);

        // ---- accumulate 81 displacements for CCH channels ----
#pragma unroll 1
        for (int c = 0; c < CCH; ++c) {
            const float* sp = sbase + c * (HR * HCP);
#pragma unroll
            for (int dy = 0; dy < ND; ++dy) {
                float row[ND + 1];
#pragma unroll
                for (int q = 0; q < 5; ++q) {
                    float2 t = *(const float2*)(sp + dy * HCP + 2 * q);
                    row[2 * q]     = t.x;
                    row[2 * q + 1] = t.y;
                }
#pragma unroll
                for (int dx = 0; dx < ND; ++dx) {
                    acc[dy][dx][0] = fmaf(a[c].x, row[dx],     acc[dy][dx][0]);
                    acc[dy][dx][1] = fmaf(a[c].y, row[dx + 1], acc[dy][dx][1]);
                }
            }
        }
    }

    // ---- epilogue: mean over channels, write [B, 81, H, W] ----
    const float scale = 1.0f / 64.0f;
    float* op = out + (((size_t)b * NK) * H_ + gy) * W_ + gx;
#pragma unroll
    for (int dy = 0; dy < ND; ++dy)
#pragma unroll
        for (int dx = 0; dx < ND; ++dx) {
            float2 v = make_float2(acc[dy][dx][0] * scale, acc[dy][dx][1] * scale);
            *(float2*)(op + (size_t)(dy * ND + dx) * plane) = v;
        }
}

extern "C" void kernel_launch(void* const* d_in, const int* in_sizes, int n_in,
                              void* d_out, int out_size, void* d_ws, size_t ws_size,
                              hipStream_t stream)
{
    const float* feat1 = (const float*)d_in[0];
    const float* feat2 = (const float*)d_in[1];
    float* out = (float*)d_out;

    dim3 grid(W_ / TW, H_ / TH, B_);   // 14 x 12 x 4 = 672 blocks
    dim3 block(NTHREADS);
    corr81_kernel<<<grid, block, 0, stream>>>(feat1, feat2, out);
}

// Round 3
// 505.698 us; speedup vs baseline: 1.0084x; 1.0084x over previous
//
#include <hip/hip_runtime.h>

namespace {
constexpr int D_  = 4;
constexpr int ND  = 9;     // 2D+1
constexpr int NK  = 81;
constexpr int B_  = 4, C_ = 64, H_ = 192, W_ = 448;

constexpr int GROUPS = 3;  // dy split into 3 groups of 3
constexpr int GDY    = 3;  // dys per group

constexpr int TH  = 8;     // output rows per block
constexpr int TXN = 16;    // threads along x
constexpr int PX  = 2;     // pixels per thread along x
constexpr int TW  = TXN * PX;        // 32
constexpr int CCH = 8;               // channels staged per round
constexpr int RG  = TH + GDY - 1;    // 10 feat2 rows per group (FIXED: was 12)
constexpr int HC  = TW + 2 * D_;     // 40
constexpr int HCP = 42;              // padded LDS row stride (float2-aligned)
constexpr int NTHREADS = TH * TXN;   // 128
constexpr int STAGE_F2 = CCH * RG * (HC / 2);   // 1600 float2 per round
static_assert(STAGE_F2 <= 13 * NTHREADS, "staging loop must cover tile");
}

__global__ __launch_bounds__(NTHREADS, 3)
void corr81_kernel(const float* __restrict__ f1, const float* __restrict__ f2,
                   float* __restrict__ out)
{
    __shared__ float s2[CCH * RG * HCP];   // 8*10*42*4 = 13440 B

    const int tid = threadIdx.x;
    const int tx  = tid & (TXN - 1);
    const int ty  = tid >> 4;              // 0..7

    const int x0 = blockIdx.x * TW;
    const int y0 = blockIdx.y * TH;
    const int bz = blockIdx.z;
    const int b  = bz / GROUPS;
    const int g  = bz - b * GROUPS;        // dy-group 0..2

    const int gx = x0 + tx * PX;
    const int gy = y0 + ty;
    const int yb = y0 + GDY * g - D_;      // first staged feat2 row

    float acc[GDY][ND][PX];
#pragma unroll
    for (int i = 0; i < GDY; ++i)
#pragma unroll
        for (int j = 0; j < ND; ++j)
#pragma unroll
            for (int p = 0; p < PX; ++p) acc[i][j][p] = 0.f;

    const size_t plane = (size_t)H_ * W_;
    const float* f1p = f1 + (((size_t)b * C_) * H_ + gy) * W_ + gx;

    // this thread's LDS compute base (channel 0, dy_local 0)
    const float* sbase = s2 + ty * HCP + tx * PX;

    for (int cc = 0; cc < C_; cc += CCH) {
        __syncthreads();  // protect previous round's LDS reads

        // ---- stage CCH channels x RG rows of feat2 (float2 granularity) ----
        // 1600 float2 over 128 threads -> 13 iterations (last partially masked)
#pragma unroll
        for (int i = 0; i < 13; ++i) {
            int l = tid + NTHREADS * i;
            if (l < STAGE_F2) {
                int c   = l / (RG * (HC / 2));            // /200
                int rem = l - c * (RG * (HC / 2));
                int r   = rem / (HC / 2);                 // /20
                int p   = rem - r * (HC / 2);
                int col = p * 2;
                int yy  = yb + r;
                int xx  = x0 - D_ + col;                  // even -> no straddle
                float2 v = make_float2(0.f, 0.f);
                if (yy >= 0 && yy < H_ && xx >= 0 && xx < W_) {
                    v = *(const float2*)(f2 + (((size_t)b * C_ + cc + c) * H_ + yy) * W_ + xx);
                }
                *(float2*)&s2[(c * RG + r) * HCP + col] = v;
            }
        }
        __syncthreads();

        // ---- feat1 values for these channels (coalesced, L3-served re-reads) ----
        float2 a[CCH];
#pragma unroll
        for (int c = 0; c < CCH; ++c)
            a[c] = *(const float2*)(f1p + (size_t)(cc + c) * plane);

        // ---- accumulate 27 displacements for CCH channels ----
#pragma unroll 1
        for (int c = 0; c < CCH; ++c) {
            const float* sp = sbase + c * (RG * HCP);
#pragma unroll
            for (int dl = 0; dl < GDY; ++dl) {
                float row[ND + 1];
#pragma unroll
                for (int q = 0; q < 5; ++q) {
                    float2 t = *(const float2*)(sp + dl * HCP + 2 * q);
                    row[2 * q]     = t.x;
                    row[2 * q + 1] = t.y;
                }
#pragma unroll
                for (int dx = 0; dx < ND; ++dx) {
                    acc[dl][dx][0] = fmaf(a[c].x, row[dx],     acc[dl][dx][0]);
                    acc[dl][dx][1] = fmaf(a[c].y, row[dx + 1], acc[dl][dx][1]);
                }
            }
        }
    }

    // ---- epilogue: mean over channels, write [B, 81, H, W] ----
    const float scale = 1.0f / (float)C_;
    float* op = out + (((size_t)b * NK) * H_ + gy) * W_ + gx;
#pragma unroll
    for (int dl = 0; dl < GDY; ++dl) {
        const int dy = GDY * g + dl;
#pragma unroll
        for (int dx = 0; dx < ND; ++dx) {
            float2 v = make_float2(acc[dl][dx][0] * scale, acc[dl][dx][1] * scale);
            *(float2*)(op + (size_t)(dy * ND + dx) * plane) = v;
        }
    }
}

extern "C" void kernel_launch(void* const* d_in, const int* in_sizes, int n_in,
                              void* d_out, int out_size, void* d_ws, size_t ws_size,
                              hipStream_t stream)
{
    const float* feat1 = (const float*)d_in[0];
    const float* feat2 = (const float*)d_in[1];
    float* out = (float*)d_out;

    dim3 grid(W_ / TW, H_ / TH, B_ * GROUPS);   // 14 x 24 x 12 = 4032 blocks
    dim3 block(NTHREADS);
    corr81_kernel<<<grid, block, 0, stream>>>(feat1, feat2, out);
}

// Round 4
// 399.068 us; speedup vs baseline: 1.2778x; 1.2672x over previous
//
#include <hip/hip_runtime.h>

namespace {
constexpr int D_  = 4;
constexpr int ND  = 9;     // 2D+1
constexpr int NK  = 81;
constexpr int B_  = 4, C_ = 64, H_ = 192, W_ = 448;

constexpr int GROUPS = 9;  // one dy per block -> acc[9][2] = 18 VGPRs, no spill

constexpr int TH  = 16;    // output rows per block
constexpr int TXN = 16;    // threads along x
constexpr int PX  = 2;     // pixels per thread along x
constexpr int TW  = TXN * PX;        // 32
constexpr int CCH = 8;               // channels staged per round
constexpr int HC  = TW + 2 * D_;     // 40 halo cols (x only; dy fixed)
constexpr int HCP = 44;              // padded LDS row stride (16B-aligned, mod32=12)
constexpr int NTHREADS = TH * TXN;   // 256
constexpr int F4ROW = HC / 4;        // 10 float4 per staged row
constexpr int STAGE_F4 = CCH * TH * F4ROW;   // 1280 float4 per round
constexpr int SITER = STAGE_F4 / NTHREADS;   // 5, exact
static_assert(SITER * NTHREADS == STAGE_F4, "exact staging coverage");
}

__global__ __launch_bounds__(NTHREADS, 4)
void corr81_kernel(const float* __restrict__ f1, const float* __restrict__ f2,
                   float* __restrict__ out)
{
    __shared__ float s2[CCH * TH * HCP];   // 8*16*44*4 = 22528 B

    const int tid = threadIdx.x;
    const int tx  = tid & (TXN - 1);
    const int ty  = tid >> 4;              // 0..15

    const int x0 = blockIdx.x * TW;
    const int y0 = blockIdx.y * TH;
    const int bz = blockIdx.z;
    const int b  = bz / GROUPS;
    const int g  = bz - b * GROUPS;        // dy index 0..8

    const int gx = x0 + tx * PX;
    const int gy = y0 + ty;
    const int yb = y0 + g - D_;            // first staged feat2 row (r=0)

    float acc[ND][PX];
#pragma unroll
    for (int j = 0; j < ND; ++j)
#pragma unroll
        for (int p = 0; p < PX; ++p) acc[j][p] = 0.f;

    const size_t plane = (size_t)H_ * W_;
    const float* f1p = f1 + (((size_t)b * C_) * H_ + gy) * W_ + gx;

    // this thread's LDS compute base (channel 0): row ty, col tx*PX
    const float* sbase = s2 + ty * HCP + tx * PX;

    for (int cc = 0; cc < C_; cc += CCH) {
        __syncthreads();  // protect previous round's LDS reads

        // ---- stage CCH channels x TH rows of feat2 (float4 granularity) ----
        // chunks are 16B-aligned and never straddle the W boundary
#pragma unroll
        for (int i = 0; i < SITER; ++i) {
            int l   = tid + NTHREADS * i;        // < 1280
            int c   = l / (TH * F4ROW);          // /160
            int rem = l - c * (TH * F4ROW);
            int r   = rem / F4ROW;               // /10
            int p   = rem - r * F4ROW;
            int col = p * 4;
            int yy  = yb + r;
            int xx  = x0 - D_ + col;
            float4 v = make_float4(0.f, 0.f, 0.f, 0.f);
            if (yy >= 0 && yy < H_ && xx >= 0 && xx < W_) {
                v = *(const float4*)(f2 + (((size_t)b * C_ + cc + c) * H_ + yy) * W_ + xx);
            }
            *(float4*)&s2[(c * TH + r) * HCP + col] = v;
        }
        __syncthreads();

        // ---- feat1 values for these channels (coalesced; L3-served re-reads) ----
        float2 a[CCH];
#pragma unroll
        for (int c = 0; c < CCH; ++c)
            a[c] = *(const float2*)(f1p + (size_t)(cc + c) * plane);

        // ---- accumulate 9 dx displacements for CCH channels ----
#pragma unroll
        for (int c = 0; c < CCH; ++c) {
            const float* sp = sbase + c * (TH * HCP);
            float row[ND + 1];
#pragma unroll
            for (int q = 0; q < 5; ++q) {
                float2 t = *(const float2*)(sp + 2 * q);
                row[2 * q]     = t.x;
                row[2 * q + 1] = t.y;
            }
#pragma unroll
            for (int dx = 0; dx < ND; ++dx) {
                acc[dx][0] = fmaf(a[c].x, row[dx],     acc[dx][0]);
                acc[dx][1] = fmaf(a[c].y, row[dx + 1], acc[dx][1]);
            }
        }
    }

    // ---- epilogue: mean over channels, write planes g*9+dx of [B, 81, H, W] ----
    const float scale = 1.0f / (float)C_;
    float* op = out + (((size_t)b * NK) * H_ + gy) * W_ + gx;
#pragma unroll
    for (int dx = 0; dx < ND; ++dx) {
        float2 v = make_float2(acc[dx][0] * scale, acc[dx][1] * scale);
        *(float2*)(op + (size_t)(g * ND + dx) * plane) = v;
    }
}

extern "C" void kernel_launch(void* const* d_in, const int* in_sizes, int n_in,
                              void* d_out, int out_size, void* d_ws, size_t ws_size,
                              hipStream_t stream)
{
    const float* feat1 = (const float*)d_in[0];
    const float* feat2 = (const float*)d_in[1];
    float* out = (float*)d_out;

    dim3 grid(W_ / TW, H_ / TH, B_ * GROUPS);   // 14 x 12 x 36 = 6048 blocks
    dim3 block(NTHREADS);
    corr81_kernel<<<grid, block, 0, stream>>>(feat1, feat2, out);
}